// Round 5
// baseline (252.188 us; speedup 1.0000x reference)
//
#include <hip/hip_runtime.h>

typedef __attribute__((ext_vector_type(8))) short short8;
typedef __attribute__((ext_vector_type(4))) float f32x4;

#define NHEADS 12
#define SEQLEN 2048
#define HEADD  64
#define DMODEL 768

// f32 -> bf16 round-to-nearest-even
__device__ __forceinline__ short cvtbf(float f) {
  unsigned u = __builtin_bit_cast(unsigned, f);
  u += 0x7fffu + ((u >> 16) & 1u);
  return (short)(u >> 16);
}

// async global->LDS, 16B per lane; lds base must be wave-uniform (HW adds lane*16)
__device__ __forceinline__ void gload16(const void* g, void* l) {
  __builtin_amdgcn_global_load_lds((const __attribute__((address_space(1))) void*)g,
                                   (__attribute__((address_space(3))) void*)l, 16, 0, 0);
}

// store high 16 bits of f32 (bf16 truncation) to LDS in ONE instruction, no VALU
__device__ __forceinline__ void ds_write_hi16(short* p, float v) {
  asm volatile("ds_write_b16_d16_hi %0, %1"
               : : "v"((__attribute__((address_space(3))) short*)p), "v"(v) : "memory");
}

// ------- kernel 1: fused prep: cast x -> bf16  +  transpose weights -> bf16 [n][k] -------
// grid 3840 x 256: bid<1536 cvt part; else transpose part (decode z,y,x).
__global__ void prep_kernel(const float* __restrict__ x,
                            const float* __restrict__ w0, const float* __restrict__ w1,
                            const float* __restrict__ w2, const float* __restrict__ w3,
                            short* __restrict__ xb, short* __restrict__ wt,
                            short* __restrict__ wot) {
  __shared__ float t[32][33];
  const int bid = blockIdx.x;
  if (bid < 1536) {
    int i = bid * 256 + threadIdx.x;
    const float* p = x + (size_t)i * 8;
    short8 v;
#pragma unroll
    for (int j = 0; j < 8; ++j) v[j] = cvtbf(p[j]);
    *(short8*)(xb + (size_t)i * 8) = v;
  } else {
    int b2 = bid - 1536;               // 0..2303
    int z = b2 / 576, rem = b2 % 576;
    int by = rem / 24, bx = rem % 24;
    const float* W = z == 0 ? w0 : z == 1 ? w1 : z == 2 ? w2 : w3;
    short* O = z < 3 ? wt + (size_t)z * (768 * 768) : wot;
    int tx = threadIdx.x & 31, ty = threadIdx.x >> 5;   // (32,8)
    int n0 = bx * 32, k0 = by * 32;
#pragma unroll
    for (int j = 0; j < 4; ++j)
      t[ty + j * 8][tx] = W[(k0 + ty + j * 8) * 768 + n0 + tx];
    __syncthreads();
#pragma unroll
    for (int j = 0; j < 4; ++j)
      O[(n0 + ty + j * 8) * 768 + k0 + tx] = cvtbf(t[tx][ty + j * 8]);
  }
}

// ---------------- 128x128 GEMM core (m97-style): C = A[128xK] * Bt[128xK]^T ----------------
__device__ __forceinline__ void gemm_core128(const short* __restrict__ A,
                                             const short* __restrict__ Bt,
                                             short* sA, short* sB,
                                             int bm, int bn, f32x4 acc[4][4]) {
  const int tid = threadIdx.x;
  const int w = tid >> 6, lane = tid & 63;
  const int quad = lane >> 4, l16 = lane & 15;
  const int wm = (w & 1) << 6, wn = (w >> 1) << 6;

  int gA[4], gB[4], lbase[4];
#pragma unroll
  for (int j = 0; j < 4; ++j) {
    int slot = w * 256 + j * 64 + lane;        // 1024 16B chunks per tile
    int r = slot >> 3;
    int c = (slot & 7) ^ (r & 7);
    gA[j] = (bm * 128 + r) * 768 + c * 8;
    gB[j] = (bn * 128 + r) * 768 + c * 8;
    lbase[j] = (w * 256 + j * 64) * 8;         // shorts; wave-uniform
  }

  for (int kt = 0; kt < 12; ++kt) {
    __syncthreads();
#pragma unroll
    for (int j = 0; j < 4; ++j) {
      gload16(A + gA[j] + kt * 64, sA + lbase[j]);
      gload16(Bt + gB[j] + kt * 64, sB + lbase[j]);
    }
    __syncthreads();
#pragma unroll
    for (int ks = 0; ks < 2; ++ks) {
      short8 a[4], b[4];
#pragma unroll
      for (int mt = 0; mt < 4; ++mt) {
        int row = wm + mt * 16 + l16;
        int cp = (ks * 4 + quad) ^ (l16 & 7);
        a[mt] = *(const short8*)(sA + row * 64 + cp * 8);
      }
#pragma unroll
      for (int nt = 0; nt < 4; ++nt) {
        int row = wn + nt * 16 + l16;
        int cp = (ks * 4 + quad) ^ (l16 & 7);
        b[nt] = *(const short8*)(sB + row * 64 + cp * 8);
      }
#pragma unroll
      for (int mt = 0; mt < 4; ++mt)
#pragma unroll
        for (int nt = 0; nt < 4; ++nt)
          acc[mt][nt] = __builtin_amdgcn_mfma_f32_16x16x32_bf16(a[mt], b[nt], acc[mt][nt], 0, 0, 0);
    }
  }
}

// ------------- 64xBN GEMM core (for oproj) -------------
template <int BN>
__device__ __forceinline__ void gemm_core64(const short* __restrict__ A,
                                            const short* __restrict__ Bt,
                                            short* sA, short* sB,
                                            int bm, int bn, f32x4 acc[2][BN / 32]) {
  constexpr int NT = BN / 32;
  const int tid = threadIdx.x;
  const int w = tid >> 6, lane = tid & 63;
  const int quad = lane >> 4, l16 = lane & 15;
  const int wm = (w & 1) * 32, wn = (w >> 1) * (BN / 2);

  int gA[2], lA[2], gB[NT], lB[NT];
#pragma unroll
  for (int j = 0; j < 2; ++j) {
    int slot = j * 256 + w * 64 + lane;
    int r = slot >> 3, c = (slot & 7) ^ (r & 7);
    gA[j] = (bm * 64 + r) * 768 + c * 8;
    lA[j] = (j * 256 + w * 64) * 8;
  }
#pragma unroll
  for (int j = 0; j < NT; ++j) {
    int slot = j * 256 + w * 64 + lane;
    int r = slot >> 3, c = (slot & 7) ^ (r & 7);
    gB[j] = (bn * BN + r) * 768 + c * 8;
    lB[j] = (j * 256 + w * 64) * 8;
  }

  for (int kt = 0; kt < 12; ++kt) {
    __syncthreads();
#pragma unroll
    for (int j = 0; j < 2; ++j) gload16(A + gA[j] + kt * 64, sA + lA[j]);
#pragma unroll
    for (int j = 0; j < NT; ++j) gload16(Bt + gB[j] + kt * 64, sB + lB[j]);
    __syncthreads();
#pragma unroll
    for (int ks = 0; ks < 2; ++ks) {
      short8 a[2], b[NT];
      int cp = (ks * 4 + quad) ^ (l16 & 7);
#pragma unroll
      for (int mt = 0; mt < 2; ++mt)
        a[mt] = *(const short8*)(sA + (wm + mt * 16 + l16) * 64 + cp * 8);
#pragma unroll
      for (int nt = 0; nt < NT; ++nt)
        b[nt] = *(const short8*)(sB + (wn + nt * 16 + l16) * 64 + cp * 8);
#pragma unroll
      for (int mt = 0; mt < 2; ++mt)
#pragma unroll
        for (int nt = 0; nt < NT; ++nt)
          acc[mt][nt] = __builtin_amdgcn_mfma_f32_16x16x32_bf16(a[mt], b[nt], acc[mt][nt], 0, 0, 0);
    }
  }
}

// ---------------- kernel 2: fused QKV projection (128x128 tiles) ----------------
// grid (32, 18): bn/6 selects segment (0=Q,1=K,2=V).
// Q pre-scaled by 0.125*log2(e). Q,K -> [b][h][s][64]; V -> [b][h][64][s].
__global__ __launch_bounds__(256, 2) void qkv_gemm(
    const short* __restrict__ A, const short* __restrict__ Bt,
    const float* __restrict__ bq, const float* __restrict__ bk, const float* __restrict__ bv,
    short* __restrict__ oq, short* __restrict__ ok, short* __restrict__ ov) {
  __shared__ short sA[128 * 64];
  __shared__ short sB[128 * 64];
  f32x4 acc[4][4];
  const f32x4 z4 = {0.f, 0.f, 0.f, 0.f};
#pragma unroll
  for (int mt = 0; mt < 4; ++mt)
#pragma unroll
    for (int nt = 0; nt < 4; ++nt) acc[mt][nt] = z4;

  const int bm = blockIdx.x, bn = blockIdx.y;
  gemm_core128(A, Bt, sA, sB, bm, bn, acc);

  const int seg = bn / 6, bn_l = bn % 6;
  const float* bias = seg == 0 ? bq : seg == 1 ? bk : bv;
  short* outp = seg == 0 ? oq : seg == 1 ? ok : ov;

  const int tid = threadIdx.x;
  const int w = tid >> 6, lane = tid & 63;
  const int quad = lane >> 4, l16 = lane & 15;
  const int wm = (w & 1) << 6, wn = (w >> 1) << 6;

#pragma unroll
  for (int nt = 0; nt < 4; ++nt) {
    int n = bn_l * 128 + wn + nt * 16 + l16;   // 0..767 within segment
    float bval = bias[n];
    int h = n >> 6, d = n & 63;
#pragma unroll
    for (int mt = 0; mt < 4; ++mt) {
      int rowb = wm + mt * 16 + quad * 4;
#pragma unroll
      for (int r = 0; r < 4; ++r) {
        int m = bm * 128 + rowb + r;
        int s = m >> 1, b = m & 1;
        float v = acc[mt][nt][r] + bval;
        if (seg == 0) v *= 0.1803368801f;      // 0.125 * log2(e)
        if (seg < 2)
          outp[((b * NHEADS + h) * SEQLEN + s) * HEADD + d] = cvtbf(v);
        else
          outp[((b * NHEADS + h) * HEADD + d) * SEQLEN + s] = cvtbf(v);
      }
    }
  }
}

// -------- attn work table: 40 entries {qj | ts<<8 | ntl<<16 | slot<<24}, heavy-first --------
// qj = 128-row q-block (0..15), tiles needed = 2*qj+2, chunks of <=8 tiles.
// slot 63 = direct-write (single chunk); else spill slot 0..35 (per bh).
#define AE(qj, ts, nt, sl) ((qj) | ((ts) << 8) | ((nt) << 16) | ((sl) << 24))
__device__ const int ATTN_TAB[40] = {
  AE(15,0,8,32), AE(15,8,8,33), AE(15,16,8,34), AE(15,24,8,35),
  AE(14,0,8,28), AE(14,8,8,29),
  AE(11,0,8,17), AE(11,8,8,18), AE(11,16,8,19),
  AE(10,0,8,14),
  AE(7,0,8,6),  AE(7,8,8,7),
  AE(3,0,8,63),
  AE(14,16,7,30), AE(14,23,7,31),
  AE(13,0,7,24), AE(13,7,7,25), AE(13,14,7,26), AE(13,21,7,27),
  AE(12,0,7,20), AE(12,7,7,21),
  AE(10,8,7,15), AE(10,15,7,16),
  AE(9,0,7,11), AE(9,7,7,12),
  AE(6,0,7,4),  AE(6,7,7,5),
  AE(12,14,6,22), AE(12,20,6,23),
  AE(9,14,6,13),
  AE(8,0,6,8), AE(8,6,6,9), AE(8,12,6,10),
  AE(5,0,6,2), AE(5,6,6,3),
  AE(2,0,6,63),
  AE(4,0,5,0), AE(4,5,5,1),
  AE(1,0,4,63),
  AE(0,0,2,63),
};
// spill-slot base per qj (qj>=4), nch = ((qj-4)>>2)+2
__device__ const int PB[16] = {0,0,0,0, 0,2,4,6, 8,11,14,17, 20,24,28,32};

// ---------------- kernel 3: split-K flash attention, 128 q-rows/block ----------------
// 4 waves x 32 q-rows. Each wave: 2 mt sub-tiles. Single-buffer K/V (32 KB LDS).
// grid 960 = 40 entries x 24 bh.
__global__ __launch_bounds__(256, 4) void attn_kernel(
    const short* __restrict__ Q, const short* __restrict__ K,
    const short* __restrict__ Vt, short* __restrict__ Y,
    float* __restrict__ Of, float* __restrict__ lf) {
  __shared__ short sK[64 * 64];    // [t][d], swizzled
  __shared__ short sV[64 * 64];    // [d][t], swizzled
  __shared__ short sP[128 * 64];   // [q][t], swizzled, wave-private rows
  const int tid = threadIdx.x;
  const int w = tid >> 6, lane = tid & 63;
  const int quad = lane >> 4, l16 = lane & 15;
  const int e = ATTN_TAB[blockIdx.x / 24];
  const int bh = blockIdx.x % 24;
  const int qj = e & 15, ts = (e >> 8) & 255, ntl = (e >> 16) & 255, slot = (e >> 24) & 255;
  const int q0 = qj << 7;
  const short* Qb = Q + (size_t)bh * (SEQLEN * HEADD);
  const short* Kb = K + (size_t)bh * (SEQLEN * HEADD);
  const short* Vb = Vt + (size_t)bh * (SEQLEN * HEADD);  // [64][2048]

  // Q fragments (A-operand, pre-scaled): rows q0 + w*32 + mt*16 + l16
  short8 aq[2][2];
#pragma unroll
  for (int mt = 0; mt < 2; ++mt)
#pragma unroll
    for (int ks = 0; ks < 2; ++ks)
      aq[mt][ks] = *(const short8*)(Qb + (q0 + w * 32 + mt * 16 + l16) * 64 + ks * 32 + quad * 8);

  const short8 bones = {0x3F80, 0x3F80, 0x3F80, 0x3F80, 0x3F80, 0x3F80, 0x3F80, 0x3F80};
  f32x4 acc_o[2][4], acc_l[2];
  const f32x4 z4 = {0.f, 0.f, 0.f, 0.f};
#pragma unroll
  for (int mt = 0; mt < 2; ++mt) {
    acc_l[mt] = z4;
#pragma unroll
    for (int nt = 0; nt < 4; ++nt) acc_o[mt][nt] = z4;
  }

  int gK[2], gV[2], lbase[2];
#pragma unroll
  for (int j = 0; j < 2; ++j) {
    int slot2 = j * 256 + w * 64 + lane;      // 512 16B chunks per 64x64 tile
    int r = slot2 >> 3, c = (slot2 & 7) ^ (r & 7);
    gK[j] = r * 64 + c * 8;
    gV[j] = r * 2048 + c * 8;
    lbase[j] = (j * 256 + w * 64) * 8;
  }

  for (int it = ts; it < ts + ntl; ++it) {
    const int t0 = it << 6;
    __syncthreads();   // all waves done reading previous tile
#pragma unroll
    for (int j = 0; j < 2; ++j) {
      gload16(Kb + t0 * 64 + gK[j], sK + lbase[j]);
      gload16(Vb + t0 + gV[j], sV + lbase[j]);
    }
    __syncthreads();   // loads drained (vmcnt0 before barrier)

    // S = Q K^T  (2 mt x 4 nt), K B-frags shared across mt
    f32x4 sc[2][4];
#pragma unroll
    for (int mt = 0; mt < 2; ++mt)
#pragma unroll
      for (int nt = 0; nt < 4; ++nt) sc[mt][nt] = z4;
#pragma unroll
    for (int ks = 0; ks < 2; ++ks) {
      int cp = (ks * 4 + quad) ^ (l16 & 7);
#pragma unroll
      for (int nt = 0; nt < 4; ++nt) {
        short8 bk = *(const short8*)(sK + (nt * 16 + l16) * 64 + cp * 8);
#pragma unroll
        for (int mt = 0; mt < 2; ++mt)
          sc[mt][nt] = __builtin_amdgcn_mfma_f32_16x16x32_bf16(aq[mt][ks], bk, sc[mt][nt], 0, 0, 0);
      }
    }

    // causal mask on diagonal tiles (it >= 2*qj)
    if (it >= 2 * qj) {
#pragma unroll
      for (int mt = 0; mt < 2; ++mt) {
        int qrow = q0 + w * 32 + mt * 16 + quad * 4;
#pragma unroll
        for (int nt = 0; nt < 4; ++nt)
#pragma unroll
          for (int r = 0; r < 4; ++r) {
            int t = t0 + nt * 16 + l16;
            if (t > qrow + r) sc[mt][nt][r] = -1e30f;
          }
      }
    }

    // p = exp2(s); truncate-store to LDS (d16_hi, zero VALU)
#pragma unroll
    for (int mt = 0; mt < 2; ++mt)
#pragma unroll
      for (int nt = 0; nt < 4; ++nt)
#pragma unroll
        for (int r = 0; r < 4; ++r) {
          float p = __builtin_amdgcn_exp2f(sc[mt][nt][r]);
          int rq = w * 32 + mt * 16 + quad * 4 + r;
          int t = nt * 16 + l16;
          int c = t >> 3;
          ds_write_hi16(&sP[rq * 64 + ((c ^ (rq & 7)) * 8 + (t & 7))], p);
        }

    // O += P V ; l += P * ones  (V B-frags shared across mt)
#pragma unroll
    for (int kst = 0; kst < 2; ++kst) {
      short8 ap[2];
#pragma unroll
      for (int mt = 0; mt < 2; ++mt) {
        int rq = w * 32 + mt * 16 + l16;
        int cpa = (kst * 4 + quad) ^ (rq & 7);
        ap[mt] = *(const short8*)(sP + rq * 64 + cpa * 8);
        acc_l[mt] = __builtin_amdgcn_mfma_f32_16x16x32_bf16(ap[mt], bones, acc_l[mt], 0, 0, 0);
      }
#pragma unroll
      for (int nt = 0; nt < 4; ++nt) {
        int row = nt * 16 + l16;
        int cv = (kst * 4 + quad) ^ (row & 7);
        short8 bv = *(const short8*)(sV + row * 64 + cv * 8);
#pragma unroll
        for (int mt = 0; mt < 2; ++mt)
          acc_o[mt][nt] = __builtin_amdgcn_mfma_f32_16x16x32_bf16(ap[mt], bv, acc_o[mt][nt], 0, 0, 0);
      }
    }
  }

  if (slot == 63) {
    // single chunk: normalize + write Y[(s*2+b)][h*64+d] bf16
    const int b = bh / NHEADS, h = bh % NHEADS;
#pragma unroll
    for (int mt = 0; mt < 2; ++mt)
#pragma unroll
      for (int r = 0; r < 4; ++r) {
        float rl = __builtin_amdgcn_rcpf(acc_l[mt][r]);
        int srow = q0 + w * 32 + mt * 16 + quad * 4 + r;
#pragma unroll
        for (int nt = 0; nt < 4; ++nt)
          Y[(srow * 2 + b) * DMODEL + h * 64 + nt * 16 + l16] = cvtbf(acc_o[mt][nt][r] * rl);
      }
  } else {
    // spill unnormalized partial (O[128x64], l[128]) f32
    float* Ob = Of + (size_t)(bh * 36 + slot) * 8192;
    float* Lb = lf + (bh * 36 + slot) * 128;
#pragma unroll
    for (int mt = 0; mt < 2; ++mt)
#pragma unroll
      for (int r = 0; r < 4; ++r) {
        int row = w * 32 + mt * 16 + quad * 4 + r;
#pragma unroll
        for (int nt = 0; nt < 4; ++nt)
          Ob[row * 64 + nt * 16 + l16] = acc_o[mt][nt][r];
        if (l16 == 0) Lb[row] = acc_l[mt][r];
      }
  }
}

// ---------------- kernel 3b: merge 2-4 partials for qj>=4 ----------------
// grid 288 = 12 qj x 24 bh; 256 threads, 32 elems each (128x64)
__global__ void attn_merge(const float* __restrict__ Of, const float* __restrict__ lf,
                           short* __restrict__ Y) {
  const int bh = blockIdx.x % 24, qj = 4 + blockIdx.x / 24;
  const int nch = ((qj - 4) >> 2) + 2;       // 2,3,4
  const int base = bh * 36 + PB[qj];
  const float* O0 = Of + (size_t)base * 8192;
  const float* L0 = lf + base * 128;
  const int b = bh / NHEADS, h = bh % NHEADS;
  const int tid = threadIdx.x;
#pragma unroll
  for (int j = 0; j < 32; ++j) {
    int idx = j * 256 + tid;
    int row = idx >> 6, col = idx & 63;
    float o = 0.f, l = 0.f;
    for (int c = 0; c < nch; ++c) {
      o += O0[c * 8192 + idx];
      l += L0[c * 128 + row];
    }
    float v = o * __builtin_amdgcn_rcpf(l);
    int srow = qj * 128 + row;
    Y[(srow * 2 + b) * DMODEL + h * 64 + col] = cvtbf(v);
  }
}

// ---------------- kernel 4: output projection (f32 out + bias) ----------------
__global__ __launch_bounds__(256, 4) void oproj_gemm(
    const short* __restrict__ A, const short* __restrict__ Bt,
    const float* __restrict__ bo, float* __restrict__ out) {
  __shared__ short sA[64 * 64];
  __shared__ short sB[64 * 64];
  f32x4 acc[2][2];
  const f32x4 z4 = {0.f, 0.f, 0.f, 0.f};
#pragma unroll
  for (int mt = 0; mt < 2; ++mt)
#pragma unroll
    for (int nt = 0; nt < 2; ++nt) acc[mt][nt] = z4;

  const int bm = blockIdx.x, bn = blockIdx.y;
  gemm_core64<64>(A, Bt, sA, sB, bm, bn, acc);

  const int tid = threadIdx.x;
  const int w = tid >> 6, lane = tid & 63;
  const int quad = lane >> 4, l16 = lane & 15;
  const int wm = (w & 1) * 32, wn = (w >> 1) * 32;

#pragma unroll
  for (int nt = 0; nt < 2; ++nt) {
    int n = bn * 64 + wn + nt * 16 + l16;
    float bval = bo[n];
#pragma unroll
    for (int mt = 0; mt < 2; ++mt) {
      int rowb = wm + mt * 16 + quad * 4;
#pragma unroll
      for (int r = 0; r < 4; ++r) {
        int m = bm * 64 + rowb + r;
        out[(size_t)m * 768 + n] = acc[mt][nt][r] + bval;
      }
    }
  }
}

extern "C" void kernel_launch(void* const* d_in, const int* in_sizes, int n_in,
                              void* d_out, int out_size, void* d_ws, size_t ws_size,
                              hipStream_t stream) {
  const float* x  = (const float*)d_in[0];
  const float* Wq = (const float*)d_in[1];
  const float* bq = (const float*)d_in[2];
  const float* Wk = (const float*)d_in[3];
  const float* bk = (const float*)d_in[4];
  const float* Wv = (const float*)d_in[5];
  const float* bv = (const float*)d_in[6];
  const float* Wo = (const float*)d_in[7];
  const float* bo = (const float*)d_in[8];
  float* out = (float*)d_out;

  short* ws  = (short*)d_ws;
  short* xb  = ws;                    // 3145728 shorts: x bf16 [4096][768]
  short* wt  = ws + 3145728;          // 1769472: [2304][768] Wq^T,Wk^T,Wv^T
  short* wot = ws + 4915200;          //  589824: Wo^T [768][768]
  short* qw  = ws + 5505024;          // 3145728: Q (pre-scaled) [b][h][s][64]
  short* kw  = ws + 8650752;          // 3145728: K [b][h][s][64]
  short* vw  = ws + 11796480;         // 3145728: V^T [b][h][64][s]
  short* yw  = ws + 14942208;         // 3145728: attn out [4096][768]
  float* Of  = (float*)(ws + 18087936); // 864 slots x 8192 f32 partial O (28.3 MB)
  float* lf  = Of + 7077888;            // 864 slots x 128 f32 partial l

  prep_kernel<<<3840, 256, 0, stream>>>(x, Wq, Wk, Wv, Wo, xb, wt, wot);
  qkv_gemm<<<dim3(32, 18), 256, 0, stream>>>(xb, wt, bq, bk, bv, qw, kw, vw);
  attn_kernel<<<960, 256, 0, stream>>>(qw, kw, vw, yw, Of, lf);
  attn_merge<<<288, 256, 0, stream>>>(Of, lf, yw);
  oproj_gemm<<<dim3(64, 12), 256, 0, stream>>>(yw, wot, bo, out);
}

// Round 6
// 208.694 us; speedup vs baseline: 1.2084x; 1.2084x over previous
//
#include <hip/hip_runtime.h>

typedef __attribute__((ext_vector_type(8))) short short8;
typedef __attribute__((ext_vector_type(4))) float f32x4;

#define NHEADS 12
#define SEQLEN 2048
#define HEADD  64
#define DMODEL 768

// f32 -> bf16 round-to-nearest-even
__device__ __forceinline__ short cvtbf(float f) {
  unsigned u = __builtin_bit_cast(unsigned, f);
  u += 0x7fffu + ((u >> 16) & 1u);
  return (short)(u >> 16);
}

// async global->LDS, 16B per lane; lds base must be wave-uniform (HW adds lane*16)
__device__ __forceinline__ void gload16(const void* g, void* l) {
  __builtin_amdgcn_global_load_lds((const __attribute__((address_space(1))) void*)g,
                                   (__attribute__((address_space(3))) void*)l, 16, 0, 0);
}

// store high 16 bits of f32 (bf16 truncation) to LDS in ONE instruction, no VALU
__device__ __forceinline__ void ds_write_hi16(short* p, float v) {
  asm volatile("ds_write_b16_d16_hi %0, %1"
               : : "v"((__attribute__((address_space(3))) short*)p), "v"(v) : "memory");
}

// ------- kernel 1: fused prep: cast x -> bf16  +  transpose weights -> bf16 [n][k] -------
// grid 3840 x 256: bid<1536 cvt part; else transpose part (decode z,y,x).
__global__ void prep_kernel(const float* __restrict__ x,
                            const float* __restrict__ w0, const float* __restrict__ w1,
                            const float* __restrict__ w2, const float* __restrict__ w3,
                            short* __restrict__ xb, short* __restrict__ wt,
                            short* __restrict__ wot) {
  __shared__ float t[32][33];
  const int bid = blockIdx.x;
  if (bid < 1536) {
    int i = bid * 256 + threadIdx.x;
    const float* p = x + (size_t)i * 8;
    short8 v;
#pragma unroll
    for (int j = 0; j < 8; ++j) v[j] = cvtbf(p[j]);
    *(short8*)(xb + (size_t)i * 8) = v;
  } else {
    int b2 = bid - 1536;               // 0..2303
    int z = b2 / 576, rem = b2 % 576;
    int by = rem / 24, bx = rem % 24;
    const float* W = z == 0 ? w0 : z == 1 ? w1 : z == 2 ? w2 : w3;
    short* O = z < 3 ? wt + (size_t)z * (768 * 768) : wot;
    int tx = threadIdx.x & 31, ty = threadIdx.x >> 5;   // (32,8)
    int n0 = bx * 32, k0 = by * 32;
#pragma unroll
    for (int j = 0; j < 4; ++j)
      t[ty + j * 8][tx] = W[(k0 + ty + j * 8) * 768 + n0 + tx];
    __syncthreads();
#pragma unroll
    for (int j = 0; j < 4; ++j)
      O[(n0 + ty + j * 8) * 768 + k0 + tx] = cvtbf(t[tx][ty + j * 8]);
  }
}

// ---------------- 128x128 GEMM core (m97-style): C = A[128xK] * Bt[128xK]^T ----------------
__device__ __forceinline__ void gemm_core128(const short* __restrict__ A,
                                             const short* __restrict__ Bt,
                                             short* sA, short* sB,
                                             int bm, int bn, f32x4 acc[4][4]) {
  const int tid = threadIdx.x;
  const int w = tid >> 6, lane = tid & 63;
  const int quad = lane >> 4, l16 = lane & 15;
  const int wm = (w & 1) << 6, wn = (w >> 1) << 6;

  int gA[4], gB[4], lbase[4];
#pragma unroll
  for (int j = 0; j < 4; ++j) {
    int slot = w * 256 + j * 64 + lane;        // 1024 16B chunks per tile
    int r = slot >> 3;
    int c = (slot & 7) ^ (r & 7);
    gA[j] = (bm * 128 + r) * 768 + c * 8;
    gB[j] = (bn * 128 + r) * 768 + c * 8;
    lbase[j] = (w * 256 + j * 64) * 8;         // shorts; wave-uniform
  }

  for (int kt = 0; kt < 12; ++kt) {
    __syncthreads();
#pragma unroll
    for (int j = 0; j < 4; ++j) {
      gload16(A + gA[j] + kt * 64, sA + lbase[j]);
      gload16(Bt + gB[j] + kt * 64, sB + lbase[j]);
    }
    __syncthreads();
#pragma unroll
    for (int ks = 0; ks < 2; ++ks) {
      short8 a[4], b[4];
#pragma unroll
      for (int mt = 0; mt < 4; ++mt) {
        int row = wm + mt * 16 + l16;
        int cp = (ks * 4 + quad) ^ (l16 & 7);
        a[mt] = *(const short8*)(sA + row * 64 + cp * 8);
      }
#pragma unroll
      for (int nt = 0; nt < 4; ++nt) {
        int row = wn + nt * 16 + l16;
        int cp = (ks * 4 + quad) ^ (l16 & 7);
        b[nt] = *(const short8*)(sB + row * 64 + cp * 8);
      }
#pragma unroll
      for (int mt = 0; mt < 4; ++mt)
#pragma unroll
        for (int nt = 0; nt < 4; ++nt)
          acc[mt][nt] = __builtin_amdgcn_mfma_f32_16x16x32_bf16(a[mt], b[nt], acc[mt][nt], 0, 0, 0);
    }
  }
}

// ------------- 64xBN GEMM core (for oproj) -------------
template <int BN>
__device__ __forceinline__ void gemm_core64(const short* __restrict__ A,
                                            const short* __restrict__ Bt,
                                            short* sA, short* sB,
                                            int bm, int bn, f32x4 acc[2][BN / 32]) {
  constexpr int NT = BN / 32;
  const int tid = threadIdx.x;
  const int w = tid >> 6, lane = tid & 63;
  const int quad = lane >> 4, l16 = lane & 15;
  const int wm = (w & 1) * 32, wn = (w >> 1) * (BN / 2);

  int gA[2], lA[2], gB[NT], lB[NT];
#pragma unroll
  for (int j = 0; j < 2; ++j) {
    int slot = j * 256 + w * 64 + lane;
    int r = slot >> 3, c = (slot & 7) ^ (r & 7);
    gA[j] = (bm * 64 + r) * 768 + c * 8;
    lA[j] = (j * 256 + w * 64) * 8;
  }
#pragma unroll
  for (int j = 0; j < NT; ++j) {
    int slot = j * 256 + w * 64 + lane;
    int r = slot >> 3, c = (slot & 7) ^ (r & 7);
    gB[j] = (bn * BN + r) * 768 + c * 8;
    lB[j] = (j * 256 + w * 64) * 8;
  }

  for (int kt = 0; kt < 12; ++kt) {
    __syncthreads();
#pragma unroll
    for (int j = 0; j < 2; ++j) gload16(A + gA[j] + kt * 64, sA + lA[j]);
#pragma unroll
    for (int j = 0; j < NT; ++j) gload16(Bt + gB[j] + kt * 64, sB + lB[j]);
    __syncthreads();
#pragma unroll
    for (int ks = 0; ks < 2; ++ks) {
      short8 a[2], b[NT];
      int cp = (ks * 4 + quad) ^ (l16 & 7);
#pragma unroll
      for (int mt = 0; mt < 2; ++mt)
        a[mt] = *(const short8*)(sA + (wm + mt * 16 + l16) * 64 + cp * 8);
#pragma unroll
      for (int nt = 0; nt < NT; ++nt)
        b[nt] = *(const short8*)(sB + (wn + nt * 16 + l16) * 64 + cp * 8);
#pragma unroll
      for (int mt = 0; mt < 2; ++mt)
#pragma unroll
        for (int nt = 0; nt < NT; ++nt)
          acc[mt][nt] = __builtin_amdgcn_mfma_f32_16x16x32_bf16(a[mt], b[nt], acc[mt][nt], 0, 0, 0);
    }
  }
}

// ---------------- kernel 2: fused QKV projection (128x128 tiles) ----------------
// grid (32, 18): bn/6 selects segment (0=Q,1=K,2=V).
// Q pre-scaled by 0.125*log2(e). Q,K -> [b][h][s][64]; V -> [b][h][64][s].
__global__ __launch_bounds__(256, 2) void qkv_gemm(
    const short* __restrict__ A, const short* __restrict__ Bt,
    const float* __restrict__ bq, const float* __restrict__ bk, const float* __restrict__ bv,
    short* __restrict__ oq, short* __restrict__ ok, short* __restrict__ ov) {
  __shared__ short sA[128 * 64];
  __shared__ short sB[128 * 64];
  f32x4 acc[4][4];
  const f32x4 z4 = {0.f, 0.f, 0.f, 0.f};
#pragma unroll
  for (int mt = 0; mt < 4; ++mt)
#pragma unroll
    for (int nt = 0; nt < 4; ++nt) acc[mt][nt] = z4;

  const int bm = blockIdx.x, bn = blockIdx.y;
  gemm_core128(A, Bt, sA, sB, bm, bn, acc);

  const int seg = bn / 6, bn_l = bn % 6;
  const float* bias = seg == 0 ? bq : seg == 1 ? bk : bv;
  short* outp = seg == 0 ? oq : seg == 1 ? ok : ov;

  const int tid = threadIdx.x;
  const int w = tid >> 6, lane = tid & 63;
  const int quad = lane >> 4, l16 = lane & 15;
  const int wm = (w & 1) << 6, wn = (w >> 1) << 6;

#pragma unroll
  for (int nt = 0; nt < 4; ++nt) {
    int n = bn_l * 128 + wn + nt * 16 + l16;   // 0..767 within segment
    float bval = bias[n];
    int h = n >> 6, d = n & 63;
#pragma unroll
    for (int mt = 0; mt < 4; ++mt) {
      int rowb = wm + mt * 16 + quad * 4;
#pragma unroll
      for (int r = 0; r < 4; ++r) {
        int m = bm * 128 + rowb + r;
        int s = m >> 1, b = m & 1;
        float v = acc[mt][nt][r] + bval;
        if (seg == 0) v *= 0.1803368801f;      // 0.125 * log2(e)
        if (seg < 2)
          outp[((b * NHEADS + h) * SEQLEN + s) * HEADD + d] = cvtbf(v);
        else
          outp[((b * NHEADS + h) * HEADD + d) * SEQLEN + s] = cvtbf(v);
      }
    }
  }
}

// -------- attn work table: 24 entries {qj | ts<<8 | ntl<<16 | slot<<24}, heavy-first --------
// qj = 128-row q-block (0..15), tiles needed = 2*qj+2, chunks of <=16 tiles.
// slot 63 = direct-write (single chunk); qj>=8 spills to slot (qj-8)*2 + c.
#define AE(qj, ts, nt, sl) ((qj) | ((ts) << 8) | ((nt) << 16) | ((sl) << 24))
__device__ const int ATTN_TAB[24] = {
  AE(7,0,16,63),
  AE(15,0,16,14), AE(15,16,16,15),
  AE(14,0,15,12), AE(14,15,15,13),
  AE(6,0,14,63),
  AE(13,0,14,10), AE(13,14,14,11),
  AE(12,0,13,8),  AE(12,13,13,9),
  AE(5,0,12,63),
  AE(11,0,12,6),  AE(11,12,12,7),
  AE(10,0,11,4),  AE(10,11,11,5),
  AE(4,0,10,63),
  AE(9,0,10,2),   AE(9,10,10,3),
  AE(8,0,9,0),    AE(8,9,9,1),
  AE(3,0,8,63),
  AE(2,0,6,63),
  AE(1,0,4,63),
  AE(0,0,2,63),
};

// ---------------- kernel 3: split-K flash attention, 128 q-rows/block ----------------
// 4 waves x 32 q-rows. Single-buffer K/V (32 KB LDS). grid 576 = 24 entries x 24 bh.
// Spills are NON-TEMPORAL (bypass L2 so K/V re-reads stay cached — round-5 lesson).
__global__ __launch_bounds__(256, 4) void attn_kernel(
    const short* __restrict__ Q, const short* __restrict__ K,
    const short* __restrict__ Vt, short* __restrict__ Y,
    float* __restrict__ Of, float* __restrict__ lf) {
  __shared__ short sK[64 * 64];    // [t][d], swizzled
  __shared__ short sV[64 * 64];    // [d][t], swizzled
  __shared__ short sP[128 * 64];   // [q][t], swizzled, wave-private rows
  const int tid = threadIdx.x;
  const int w = tid >> 6, lane = tid & 63;
  const int quad = lane >> 4, l16 = lane & 15;
  const int e = ATTN_TAB[blockIdx.x / 24];
  const int bh = blockIdx.x % 24;
  const int qj = e & 15, ts = (e >> 8) & 255, ntl = (e >> 16) & 255, slot = (e >> 24) & 255;
  const int q0 = qj << 7;
  const short* Qb = Q + (size_t)bh * (SEQLEN * HEADD);
  const short* Kb = K + (size_t)bh * (SEQLEN * HEADD);
  const short* Vb = Vt + (size_t)bh * (SEQLEN * HEADD);  // [64][2048]

  // Q fragments (A-operand, pre-scaled): rows q0 + w*32 + mt*16 + l16
  short8 aq[2][2];
#pragma unroll
  for (int mt = 0; mt < 2; ++mt)
#pragma unroll
    for (int ks = 0; ks < 2; ++ks)
      aq[mt][ks] = *(const short8*)(Qb + (q0 + w * 32 + mt * 16 + l16) * 64 + ks * 32 + quad * 8);

  const short8 bones = {0x3F80, 0x3F80, 0x3F80, 0x3F80, 0x3F80, 0x3F80, 0x3F80, 0x3F80};
  f32x4 acc_o[2][4], acc_l[2];
  const f32x4 z4 = {0.f, 0.f, 0.f, 0.f};
#pragma unroll
  for (int mt = 0; mt < 2; ++mt) {
    acc_l[mt] = z4;
#pragma unroll
    for (int nt = 0; nt < 4; ++nt) acc_o[mt][nt] = z4;
  }

  int gK[2], gV[2], lbase[2];
#pragma unroll
  for (int j = 0; j < 2; ++j) {
    int slot2 = j * 256 + w * 64 + lane;      // 512 16B chunks per 64x64 tile
    int r = slot2 >> 3, c = (slot2 & 7) ^ (r & 7);
    gK[j] = r * 64 + c * 8;
    gV[j] = r * 2048 + c * 8;
    lbase[j] = (j * 256 + w * 64) * 8;
  }

  for (int it = ts; it < ts + ntl; ++it) {
    const int t0 = it << 6;
    __syncthreads();   // all waves done reading previous tile
#pragma unroll
    for (int j = 0; j < 2; ++j) {
      gload16(Kb + t0 * 64 + gK[j], sK + lbase[j]);
      gload16(Vb + t0 + gV[j], sV + lbase[j]);
    }
    __syncthreads();   // loads drained (vmcnt0 before barrier)

    // S = Q K^T  (2 mt x 4 nt), K B-frags shared across mt
    f32x4 sc[2][4];
#pragma unroll
    for (int mt = 0; mt < 2; ++mt)
#pragma unroll
      for (int nt = 0; nt < 4; ++nt) sc[mt][nt] = z4;
#pragma unroll
    for (int ks = 0; ks < 2; ++ks) {
      int cp = (ks * 4 + quad) ^ (l16 & 7);
#pragma unroll
      for (int nt = 0; nt < 4; ++nt) {
        short8 bk = *(const short8*)(sK + (nt * 16 + l16) * 64 + cp * 8);
#pragma unroll
        for (int mt = 0; mt < 2; ++mt)
          sc[mt][nt] = __builtin_amdgcn_mfma_f32_16x16x32_bf16(aq[mt][ks], bk, sc[mt][nt], 0, 0, 0);
      }
    }

    // causal mask on diagonal tiles (it >= 2*qj)
    if (it >= 2 * qj) {
#pragma unroll
      for (int mt = 0; mt < 2; ++mt) {
        int qrow = q0 + w * 32 + mt * 16 + quad * 4;
#pragma unroll
        for (int nt = 0; nt < 4; ++nt)
#pragma unroll
          for (int r = 0; r < 4; ++r) {
            int t = t0 + nt * 16 + l16;
            if (t > qrow + r) sc[mt][nt][r] = -1e30f;
          }
      }
    }

    // p = exp2(s); truncate-store to LDS (d16_hi, zero VALU)
#pragma unroll
    for (int mt = 0; mt < 2; ++mt)
#pragma unroll
      for (int nt = 0; nt < 4; ++nt)
#pragma unroll
        for (int r = 0; r < 4; ++r) {
          float p = __builtin_amdgcn_exp2f(sc[mt][nt][r]);
          int rq = w * 32 + mt * 16 + quad * 4 + r;
          int t = nt * 16 + l16;
          int c = t >> 3;
          ds_write_hi16(&sP[rq * 64 + ((c ^ (rq & 7)) * 8 + (t & 7))], p);
        }

    // O += P V ; l += P * ones  (V B-frags shared across mt)
#pragma unroll
    for (int kst = 0; kst < 2; ++kst) {
      short8 ap[2];
#pragma unroll
      for (int mt = 0; mt < 2; ++mt) {
        int rq = w * 32 + mt * 16 + l16;
        int cpa = (kst * 4 + quad) ^ (rq & 7);
        ap[mt] = *(const short8*)(sP + rq * 64 + cpa * 8);
        acc_l[mt] = __builtin_amdgcn_mfma_f32_16x16x32_bf16(ap[mt], bones, acc_l[mt], 0, 0, 0);
      }
#pragma unroll
      for (int nt = 0; nt < 4; ++nt) {
        int row = nt * 16 + l16;
        int cv = (kst * 4 + quad) ^ (row & 7);
        short8 bv = *(const short8*)(sV + row * 64 + cv * 8);
#pragma unroll
        for (int mt = 0; mt < 2; ++mt)
          acc_o[mt][nt] = __builtin_amdgcn_mfma_f32_16x16x32_bf16(ap[mt], bv, acc_o[mt][nt], 0, 0, 0);
      }
    }
  }

  if (slot == 63) {
    // single chunk: normalize + write Y[(s*2+b)][h*64+d] bf16
    const int b = bh / NHEADS, h = bh % NHEADS;
#pragma unroll
    for (int mt = 0; mt < 2; ++mt)
#pragma unroll
      for (int r = 0; r < 4; ++r) {
        float rl = __builtin_amdgcn_rcpf(acc_l[mt][r]);
        int srow = q0 + w * 32 + mt * 16 + quad * 4 + r;
#pragma unroll
        for (int nt = 0; nt < 4; ++nt)
          Y[(srow * 2 + b) * DMODEL + h * 64 + nt * 16 + l16] = cvtbf(acc_o[mt][nt][r] * rl);
      }
  } else {
    // spill unnormalized partial (O[128x64], l[128]) f32 — NON-TEMPORAL
    float* Ob = Of + (size_t)(bh * 16 + slot) * 8192;
    float* Lb = lf + (bh * 16 + slot) * 128;
#pragma unroll
    for (int mt = 0; mt < 2; ++mt)
#pragma unroll
      for (int r = 0; r < 4; ++r) {
        int row = w * 32 + mt * 16 + quad * 4 + r;
#pragma unroll
        for (int nt = 0; nt < 4; ++nt)
          __builtin_nontemporal_store(acc_o[mt][nt][r], &Ob[row * 64 + nt * 16 + l16]);
        if (l16 == 0) __builtin_nontemporal_store(acc_l[mt][r], &Lb[row]);
      }
  }
}

// ---------------- kernel 3b: merge 2 partials for qj>=8 ----------------
// grid 192 = 8 qj x 24 bh; 256 threads, 32 elems each (128x64)
__global__ void attn_merge(const float* __restrict__ Of, const float* __restrict__ lf,
                           short* __restrict__ Y) {
  const int bh = blockIdx.x % 24, qj = 8 + blockIdx.x / 24;
  const int base = bh * 16 + (qj - 8) * 2;
  const float* O0 = Of + (size_t)base * 8192;
  const float* L0 = lf + base * 128;
  const int b = bh / NHEADS, h = bh % NHEADS;
  const int tid = threadIdx.x;
#pragma unroll
  for (int j = 0; j < 32; ++j) {
    int idx = j * 256 + tid;
    int row = idx >> 6, col = idx & 63;
    float o = __builtin_nontemporal_load(&O0[idx]) +
              __builtin_nontemporal_load(&O0[8192 + idx]);
    float l = L0[row] + L0[128 + row];
    float v = o * __builtin_amdgcn_rcpf(l);
    int srow = qj * 128 + row;
    Y[(srow * 2 + b) * DMODEL + h * 64 + col] = cvtbf(v);
  }
}

// ---------------- kernel 4: output projection (f32 out + bias) ----------------
__global__ __launch_bounds__(256, 4) void oproj_gemm(
    const short* __restrict__ A, const short* __restrict__ Bt,
    const float* __restrict__ bo, float* __restrict__ out) {
  __shared__ short sA[64 * 64];
  __shared__ short sB[64 * 64];
  f32x4 acc[2][2];
  const f32x4 z4 = {0.f, 0.f, 0.f, 0.f};
#pragma unroll
  for (int mt = 0; mt < 2; ++mt)
#pragma unroll
    for (int nt = 0; nt < 2; ++nt) acc[mt][nt] = z4;

  const int bm = blockIdx.x, bn = blockIdx.y;
  gemm_core64<64>(A, Bt, sA, sB, bm, bn, acc);

  const int tid = threadIdx.x;
  const int w = tid >> 6, lane = tid & 63;
  const int quad = lane >> 4, l16 = lane & 15;
  const int wm = (w & 1) * 32, wn = (w >> 1) * 32;

#pragma unroll
  for (int nt = 0; nt < 2; ++nt) {
    int n = bn * 64 + wn + nt * 16 + l16;
    float bval = bo[n];
#pragma unroll
    for (int mt = 0; mt < 2; ++mt) {
      int rowb = wm + mt * 16 + quad * 4;
#pragma unroll
      for (int r = 0; r < 4; ++r) {
        int m = bm * 64 + rowb + r;
        out[(size_t)m * 768 + n] = acc[mt][nt][r] + bval;
      }
    }
  }
}

extern "C" void kernel_launch(void* const* d_in, const int* in_sizes, int n_in,
                              void* d_out, int out_size, void* d_ws, size_t ws_size,
                              hipStream_t stream) {
  const float* x  = (const float*)d_in[0];
  const float* Wq = (const float*)d_in[1];
  const float* bq = (const float*)d_in[2];
  const float* Wk = (const float*)d_in[3];
  const float* bk = (const float*)d_in[4];
  const float* Wv = (const float*)d_in[5];
  const float* bv = (const float*)d_in[6];
  const float* Wo = (const float*)d_in[7];
  const float* bo = (const float*)d_in[8];
  float* out = (float*)d_out;

  short* ws  = (short*)d_ws;
  short* xb  = ws;                    // 3145728 shorts: x bf16 [4096][768]
  short* wt  = ws + 3145728;          // 1769472: [2304][768] Wq^T,Wk^T,Wv^T
  short* wot = ws + 4915200;          //  589824: Wo^T [768][768]
  short* qw  = ws + 5505024;          // 3145728: Q (pre-scaled) [b][h][s][64]
  short* kw  = ws + 8650752;          // 3145728: K [b][h][s][64]
  short* vw  = ws + 11796480;         // 3145728: V^T [b][h][64][s]
  short* yw  = ws + 14942208;         // 3145728: attn out [4096][768]
  float* Of  = (float*)(ws + 18087936); // 384 slots x 8192 f32 partial O (12.6 MB)
  float* lf  = Of + 3145728;            // 384 slots x 128 f32 partial l

  prep_kernel<<<3840, 256, 0, stream>>>(x, Wq, Wk, Wv, Wo, xb, wt, wot);
  qkv_gemm<<<dim3(32, 18), 256, 0, stream>>>(xb, wt, bq, bk, bv, qw, kw, vw);
  attn_kernel<<<576, 256, 0, stream>>>(qw, kw, vw, yw, Of, lf);
  attn_merge<<<192, 256, 0, stream>>>(Of, lf, yw);
  oproj_gemm<<<dim3(64, 12), 256, 0, stream>>>(yw, wot, bo, out);
}